// Round 6
// baseline (11930.554 us; speedup 1.0000x reference)
//
#include <hip/hip_runtime.h>

typedef unsigned short u16;
typedef unsigned int   u32;
typedef __attribute__((ext_vector_type(8))) u16   u16x8;
typedef __attribute__((ext_vector_type(8))) __bf16 bf16x8;
typedef __attribute__((ext_vector_type(4))) float  floatx4;
typedef __attribute__((ext_vector_type(4))) u32   u32x4;

#define TT 512     // seq len
#define ROWSP 520  // padded u16 row stride (1040 B = 260 dwords, 260%32=4 -> even bank spread)

// ---------- helpers ----------
__device__ __forceinline__ u16 f2bf(float f) {
  u32 u = __builtin_bit_cast(u32, f);
  u32 r = u + 0x7fffu + ((u >> 16) & 1u);   // round-to-nearest-even
  return (u16)(r >> 16);
}
__device__ __forceinline__ float bf2f(u16 h) {
  return __builtin_bit_cast(float, ((u32)h) << 16);
}
__device__ __forceinline__ float fast_tanh(float x) {
  float xc = fminf(fmaxf(x, -12.f), 12.f);
  float e = __expf(2.f * xc);
  return __fdividef(e - 1.f, e + 1.f);
}

// ---------- prep: convert weights to bf16, sum biases ----------
// wbf layout: [wih0 | whh0 | wih1 | whh1], each 512*512
__global__ __launch_bounds__(256)
void prep_kernel(const float* __restrict__ W_ih, const float* __restrict__ W_hh,
                 const float* __restrict__ b_ih, const float* __restrict__ b_hh,
                 u16* __restrict__ wbf, float* __restrict__ bsum) {
  int idx = blockIdx.x * blockDim.x + threadIdx.x;
  int stride = gridDim.x * blockDim.x;
  for (int i = idx; i < 4 * 262144; i += stride) {
    int mat = i >> 18;
    int off = i & 262143;
    const float* src = (mat == 0) ? W_ih : (mat == 1) ? W_hh
                     : (mat == 2) ? (W_ih + 262144) : (W_hh + 262144);
    wbf[i] = f2bf(src[off]);
  }
  if (idx < 1024) bsum[idx] = b_ih[idx] + b_hh[idx];
}

// ---------- pre-activation GEMM ----------
// Xpre[m][n] = A[m][:] @ W[n][:] + bsum[n],  M=T*B (m = t*64+b), K=512, N=512
// mode 0: A row = emb[x[b][t]] (fp32 -> bf16)
// mode 1: A row = histhi[m][0:512] (bf16 u16, contiguous) -- hi part of h0(t)
__global__ __launch_bounds__(256, 2)
void gemm_pre(const u16* __restrict__ Bw, const float* __restrict__ bsum,
              const float* __restrict__ embsrc, const int* __restrict__ xtok,
              const u16* __restrict__ histhi, float* __restrict__ Xpre, int mode) {
  __shared__ u16 As[128][40];
  __shared__ u16 Bs[128][40];
  const int tid = threadIdx.x;
  const int wave = tid >> 6, lane = tid & 63;
  const int quad = lane >> 4, l16 = lane & 15;
  const int mtile = blockIdx.x >> 2, ntile = blockIdx.x & 3;
  const int m0 = mtile * 128, n0 = ntile * 128;
  const int srow = tid >> 1, half = tid & 1;

  const float* aF = nullptr; const u16* aH = nullptr;
  {
    const int grow = m0 + srow;
    if (mode == 0) {
      const int t = grow >> 6, b = grow & 63;
      const int tok = xtok[b * TT + t];
      aF = embsrc + (size_t)tok * 512 + half * 16;
    } else {
      aH = histhi + (size_t)grow * 512 + half * 16;
    }
  }
  const u16* bptr = Bw + (size_t)(n0 + srow) * 512 + half * 16;

  floatx4 acc[2][8];
#pragma unroll
  for (int a = 0; a < 2; a++)
#pragma unroll
    for (int b = 0; b < 8; b++) acc[a][b] = (floatx4){0.f, 0.f, 0.f, 0.f};

  for (int ks = 0; ks < 16; ks++) {
    const int k0 = ks * 32;
    u32 packed[8];
    if (mode == 0) {
      const float4* p = (const float4*)(aF + k0);
      float4 f0 = p[0], f1 = p[1], f2 = p[2], f3 = p[3];
      float vals[16] = {f0.x, f0.y, f0.z, f0.w, f1.x, f1.y, f1.z, f1.w,
                        f2.x, f2.y, f2.z, f2.w, f3.x, f3.y, f3.z, f3.w};
#pragma unroll
      for (int j = 0; j < 8; j++)
        packed[j] = (u32)f2bf(vals[2 * j]) | ((u32)f2bf(vals[2 * j + 1]) << 16);
    } else {
      const u32x4* p = (const u32x4*)(aH + k0);
      u32x4 q0 = p[0], q1 = p[1];
      packed[0] = q0[0]; packed[1] = q0[1]; packed[2] = q0[2]; packed[3] = q0[3];
      packed[4] = q1[0]; packed[5] = q1[1]; packed[6] = q1[2]; packed[7] = q1[3];
    }
    {
      u32x4* adst = (u32x4*)&As[srow][half * 16];
      adst[0] = (u32x4){packed[0], packed[1], packed[2], packed[3]};
      adst[1] = (u32x4){packed[4], packed[5], packed[6], packed[7]};
    }
    {
      const u32x4* bp = (const u32x4*)(bptr + k0);
      u32x4 b0 = bp[0], b1 = bp[1];
      u32x4* bdst = (u32x4*)&Bs[srow][half * 16];
      bdst[0] = b0; bdst[1] = b1;
    }
    __syncthreads();
    bf16x8 afr[2], bfr[8];
#pragma unroll
    for (int mt = 0; mt < 2; mt++)
      afr[mt] = __builtin_bit_cast(bf16x8, *(const u16x8*)&As[wave * 32 + mt * 16 + l16][quad * 8]);
#pragma unroll
    for (int nt = 0; nt < 8; nt++)
      bfr[nt] = __builtin_bit_cast(bf16x8, *(const u16x8*)&Bs[nt * 16 + l16][quad * 8]);
#pragma unroll
    for (int mt = 0; mt < 2; mt++)
#pragma unroll
      for (int nt = 0; nt < 8; nt++)
        acc[mt][nt] = __builtin_amdgcn_mfma_f32_16x16x32_bf16(afr[mt], bfr[nt], acc[mt][nt], 0, 0, 0);
    __syncthreads();
  }
  float bs[8];
#pragma unroll
  for (int nt = 0; nt < 8; nt++) bs[nt] = bsum[n0 + nt * 16 + l16];
#pragma unroll
  for (int mt = 0; mt < 2; mt++)
#pragma unroll
    for (int nt = 0; nt < 8; nt++)
#pragma unroll
      for (int i = 0; i < 4; i++) {
        const int gm = m0 + wave * 32 + mt * 16 + quad * 4 + i;
        Xpre[(size_t)gm * 512 + n0 + nt * 16 + l16] = acc[mt][nt][i] + bs[nt];
      }
}

// ---------- recurrence pass: LDS-only exchange, zero inter-wg communication ----------
// 4 wgs x 512 threads. wg owns batch rows 16*wg .. 16*wg+15 (rows are independent!).
// 8 waves, wave wv owns hidden cols wv*64 .. +63, W-slice resident in 256 VGPRs
// (non-duplicated B-frags, R4-proven). h kept as hi+lo bf16 (near-fp32 recurrence)
// in double-buffered LDS SoA streams. One __syncthreads per step.
__global__ __launch_bounds__(512, 1)
void rnn_lds(const u16* __restrict__ Whh, const float* __restrict__ Xpre,
             const int* __restrict__ lengths, u16* __restrict__ histhi,
             float* __restrict__ out_last, float* __restrict__ out_hidden) {
  __shared__ u16 Ab[2][2][16][ROWSP];   // [buf][hi/lo][row][col], 66,560 B
  const int tid = threadIdx.x;
  const int wv = tid >> 6, lane = tid & 63;
  const int quad = lane >> 4, l16 = lane & 15;
  const int wg = blockIdx.x;
  const int colbase = wv * 64;

  // W-slice fragments: wfrag[nt][s] = W[colbase+nt*16+l16][s*32 + quad*8 .. +7]
  bf16x8 wfrag[4][16];
#pragma unroll
  for (int nt = 0; nt < 4; nt++) {
    const u16* wrow = Whh + (size_t)(colbase + nt * 16 + l16) * 512 + quad * 8;
#pragma unroll
    for (int s = 0; s < 16; s++)
      wfrag[nt][s] = __builtin_bit_cast(bf16x8, *(const u16x8*)(wrow + s * 32));
  }

  int lens[4];
  float hcur[4][4];
#pragma unroll
  for (int i = 0; i < 4; i++) {
    lens[i] = lengths[wg * 16 + quad * 4 + i];
#pragma unroll
    for (int nt = 0; nt < 4; nt++) hcur[nt][i] = 0.f;
  }

  // h(-1) = 0 in buffer 0
  for (int i = tid; i < 2 * 16 * ROWSP; i += 512) (&Ab[0][0][0][0])[i] = 0;
  __syncthreads();

  // Xpre for step 0
  float pre[4][4];
#pragma unroll
  for (int nt = 0; nt < 4; nt++)
#pragma unroll
    for (int i = 0; i < 4; i++)
      pre[nt][i] = Xpre[(size_t)(wg * 16 + quad * 4 + i) * 512 + colbase + nt * 16 + l16];

  for (int t = 0; t < TT; t++) {
    const int cur = t & 1, nxt = cur ^ 1;
    floatx4 ac[4];
#pragma unroll
    for (int nt = 0; nt < 4; nt++) ac[nt] = (floatx4){0.f, 0.f, 0.f, 0.f};

    const u16* ahi = &Ab[cur][0][l16][quad * 8];
    const u16* alo = &Ab[cur][1][l16][quad * 8];
#pragma unroll
    for (int s = 0; s < 16; s++) {
      bf16x8 a = __builtin_bit_cast(bf16x8, *(const u16x8*)(ahi + s * 32));
#pragma unroll
      for (int nt = 0; nt < 4; nt++)
        ac[nt] = __builtin_amdgcn_mfma_f32_16x16x32_bf16(a, wfrag[nt][s], ac[nt], 0, 0, 0);
    }
#pragma unroll
    for (int s = 0; s < 16; s++) {
      bf16x8 a = __builtin_bit_cast(bf16x8, *(const u16x8*)(alo + s * 32));
#pragma unroll
      for (int nt = 0; nt < 4; nt++)
        ac[nt] = __builtin_amdgcn_mfma_f32_16x16x32_bf16(a, wfrag[nt][s], ac[nt], 0, 0, 0);
    }

    // prefetch Xpre(t+1) while MFMA results settle
    float pnx[4][4];
    {
      const int tp = (t + 1 < TT) ? t + 1 : TT - 1;
#pragma unroll
      for (int nt = 0; nt < 4; nt++)
#pragma unroll
        for (int i = 0; i < 4; i++)
          pnx[nt][i] = Xpre[(size_t)(tp * 64 + wg * 16 + quad * 4 + i) * 512
                            + colbase + nt * 16 + l16];
    }

    // epilogue: tanh + mask; write h(t) to other LDS buffer (+ global hist for L0)
#pragma unroll
    for (int nt = 0; nt < 4; nt++) {
      const int col = colbase + nt * 16 + l16;
#pragma unroll
      for (int i = 0; i < 4; i++) {
        const int row = quad * 4 + i;
        const float vs = ac[nt][i] + pre[nt][i];
        const float th = fast_tanh(vs);
        const float nv = (t < lens[i]) ? th : hcur[nt][i];
        hcur[nt][i] = nv;
        const u16 hi = f2bf(nv);
        const u16 lo = f2bf(nv - bf2f(hi));
        Ab[nxt][0][row][col] = hi;
        Ab[nxt][1][row][col] = lo;
        if (histhi)
          histhi[(size_t)(t * 64 + wg * 16 + row) * 512 + col] = hi;
      }
    }
    __syncthreads();
#pragma unroll
    for (int nt = 0; nt < 4; nt++)
#pragma unroll
      for (int i = 0; i < 4; i++) pre[nt][i] = pnx[nt][i];
  }

  // final hidden state
#pragma unroll
  for (int nt = 0; nt < 4; nt++) {
    const int col = colbase + nt * 16 + l16;
#pragma unroll
    for (int i = 0; i < 4; i++) {
      const int b = wg * 16 + quad * 4 + i;
      if (out_hidden) out_hidden[(size_t)b * 1024 + col] = hcur[nt][i];
      if (out_last)   out_last[(size_t)b * 512 + col] = hcur[nt][i];
    }
  }
}

// ---------- launch ----------
extern "C" void kernel_launch(void* const* d_in, const int* in_sizes, int n_in,
                              void* d_out, int out_size, void* d_ws, size_t ws_size,
                              hipStream_t stream) {
  const int*   x   = (const int*)d_in[0];
  const int*   len = (const int*)d_in[1];
  const float* emb = (const float*)d_in[2];
  const float* Wih = (const float*)d_in[3];
  const float* Whh = (const float*)d_in[4];
  const float* bih = (const float*)d_in[5];
  const float* bhh = (const float*)d_in[6];
  float* out = (float*)d_out;

  char* ws = (char*)d_ws;
  float* Xpre   = (float*)(ws);                  // 67,108,864 B (T*B*512 fp32), reused by both layers
  u16*   histhi = (u16*)(ws + 67108864);         // 33,554,432 B (T*B*512 bf16-hi of h0)
  u16*   wbf    = (u16*)(ws + 100663296);        //  2,097,152 B
  float* bsum   = (float*)(ws + 102760448);      //      4,096 B

  hipLaunchKernelGGL(prep_kernel, dim3(512), dim3(256), 0, stream,
                     Wih, Whh, bih, bhh, wbf, bsum);
  // layer 0 pre-activations: emb-gather GEMM
  hipLaunchKernelGGL(gemm_pre, dim3(1024), dim3(256), 0, stream,
                     wbf /*wih0*/, bsum, emb, x, (const u16*)nullptr, Xpre, 0);
  // layer 0 recurrence (writes h0-hi history for layer 1's pre-GEMM)
  hipLaunchKernelGGL(rnn_lds, dim3(4), dim3(512), 0, stream,
                     wbf + 262144 /*whh0*/, Xpre, len, histhi,
                     (float*)nullptr, out + 32768 /*hidden[:,0,:]*/);
  // layer 1 pre-activations: h0-hi GEMM
  hipLaunchKernelGGL(gemm_pre, dim3(1024), dim3(256), 0, stream,
                     wbf + 524288 /*wih1*/, bsum + 512,
                     (const float*)nullptr, (const int*)nullptr, histhi, Xpre, 1);
  // layer 1 recurrence
  hipLaunchKernelGGL(rnn_lds, dim3(4), dim3(512), 0, stream,
                     wbf + 786432 /*whh1*/, Xpre, len, (u16*)nullptr,
                     out /*h_last*/, out + 32768 + 512 /*hidden[:,1,:]*/);
}

// Round 7
// 10072.161 us; speedup vs baseline: 1.1845x; 1.1845x over previous
//
#include <hip/hip_runtime.h>

typedef unsigned short u16;
typedef unsigned int   u32;
typedef __attribute__((ext_vector_type(8))) u16   u16x8;
typedef __attribute__((ext_vector_type(8))) __bf16 bf16x8;
typedef __attribute__((ext_vector_type(4))) float  floatx4;
typedef __attribute__((ext_vector_type(4))) u32   u32x4;

#define TT 512     // seq len
#define ROWSP 522  // u16 row stride = 261 dwords, 261 % 32 = 5 -> exact 2-way (free) read banking

// ---------- helpers ----------
__device__ __forceinline__ u16 f2bf(float f) {
  u32 u = __builtin_bit_cast(u32, f);
  u32 r = u + 0x7fffu + ((u >> 16) & 1u);   // round-to-nearest-even
  return (u16)(r >> 16);
}
__device__ __forceinline__ float bf2f(u16 h) {
  return __builtin_bit_cast(float, ((u32)h) << 16);
}
__device__ __forceinline__ float fast_tanh(float x) {
  float xc = fminf(fmaxf(x, -12.f), 12.f);
  float e = __expf(2.f * xc);
  return __fdividef(e - 1.f, e + 1.f);
}
// LDS-only barrier: drains ds ops, leaves global loads/stores in flight
#define LDS_BARRIER() asm volatile("s_waitcnt lgkmcnt(0)\n\ts_barrier" ::: "memory")

// ---------- prep: convert weights to bf16, sum biases ----------
// wbf layout: [wih0 | whh0 | wih1 | whh1], each 512*512
__global__ __launch_bounds__(256)
void prep_kernel(const float* __restrict__ W_ih, const float* __restrict__ W_hh,
                 const float* __restrict__ b_ih, const float* __restrict__ b_hh,
                 u16* __restrict__ wbf, float* __restrict__ bsum) {
  int idx = blockIdx.x * blockDim.x + threadIdx.x;
  int stride = gridDim.x * blockDim.x;
  for (int i = idx; i < 4 * 262144; i += stride) {
    int mat = i >> 18;
    int off = i & 262143;
    const float* src = (mat == 0) ? W_ih : (mat == 1) ? W_hh
                     : (mat == 2) ? (W_ih + 262144) : (W_hh + 262144);
    wbf[i] = f2bf(src[off]);
  }
  if (idx < 1024) bsum[idx] = b_ih[idx] + b_hh[idx];
}

// ---------- pre-activation GEMM ----------
// Xpre[m][n] = A[m][:] @ W[n][:] + bsum[n],  M=T*B (m = t*64+b), K=512, N=512
// mode 0: A row = emb[x[b][t]] (fp32 -> bf16)
// mode 1: A row = histhi[m][0:512] (bf16 u16, contiguous) -- hi part of h0(t)
__global__ __launch_bounds__(256, 2)
void gemm_pre(const u16* __restrict__ Bw, const float* __restrict__ bsum,
              const float* __restrict__ embsrc, const int* __restrict__ xtok,
              const u16* __restrict__ histhi, float* __restrict__ Xpre, int mode) {
  __shared__ u16 As[128][40];
  __shared__ u16 Bs[128][40];
  const int tid = threadIdx.x;
  const int wave = tid >> 6, lane = tid & 63;
  const int quad = lane >> 4, l16 = lane & 15;
  const int mtile = blockIdx.x >> 2, ntile = blockIdx.x & 3;
  const int m0 = mtile * 128, n0 = ntile * 128;
  const int srow = tid >> 1, half = tid & 1;

  const float* aF = nullptr; const u16* aH = nullptr;
  {
    const int grow = m0 + srow;
    if (mode == 0) {
      const int t = grow >> 6, b = grow & 63;
      const int tok = xtok[b * TT + t];
      aF = embsrc + (size_t)tok * 512 + half * 16;
    } else {
      aH = histhi + (size_t)grow * 512 + half * 16;
    }
  }
  const u16* bptr = Bw + (size_t)(n0 + srow) * 512 + half * 16;

  floatx4 acc[2][8];
#pragma unroll
  for (int a = 0; a < 2; a++)
#pragma unroll
    for (int b = 0; b < 8; b++) acc[a][b] = (floatx4){0.f, 0.f, 0.f, 0.f};

  for (int ks = 0; ks < 16; ks++) {
    const int k0 = ks * 32;
    u32 packed[8];
    if (mode == 0) {
      const float4* p = (const float4*)(aF + k0);
      float4 f0 = p[0], f1 = p[1], f2 = p[2], f3 = p[3];
      float vals[16] = {f0.x, f0.y, f0.z, f0.w, f1.x, f1.y, f1.z, f1.w,
                        f2.x, f2.y, f2.z, f2.w, f3.x, f3.y, f3.z, f3.w};
#pragma unroll
      for (int j = 0; j < 8; j++)
        packed[j] = (u32)f2bf(vals[2 * j]) | ((u32)f2bf(vals[2 * j + 1]) << 16);
    } else {
      const u32x4* p = (const u32x4*)(aH + k0);
      u32x4 q0 = p[0], q1 = p[1];
      packed[0] = q0[0]; packed[1] = q0[1]; packed[2] = q0[2]; packed[3] = q0[3];
      packed[4] = q1[0]; packed[5] = q1[1]; packed[6] = q1[2]; packed[7] = q1[3];
    }
    {
      u32x4* adst = (u32x4*)&As[srow][half * 16];
      adst[0] = (u32x4){packed[0], packed[1], packed[2], packed[3]};
      adst[1] = (u32x4){packed[4], packed[5], packed[6], packed[7]};
    }
    {
      const u32x4* bp = (const u32x4*)(bptr + k0);
      u32x4 b0 = bp[0], b1 = bp[1];
      u32x4* bdst = (u32x4*)&Bs[srow][half * 16];
      bdst[0] = b0; bdst[1] = b1;
    }
    __syncthreads();
    bf16x8 afr[2], bfr[8];
#pragma unroll
    for (int mt = 0; mt < 2; mt++)
      afr[mt] = __builtin_bit_cast(bf16x8, *(const u16x8*)&As[wave * 32 + mt * 16 + l16][quad * 8]);
#pragma unroll
    for (int nt = 0; nt < 8; nt++)
      bfr[nt] = __builtin_bit_cast(bf16x8, *(const u16x8*)&Bs[nt * 16 + l16][quad * 8]);
#pragma unroll
    for (int mt = 0; mt < 2; mt++)
#pragma unroll
      for (int nt = 0; nt < 8; nt++)
        acc[mt][nt] = __builtin_amdgcn_mfma_f32_16x16x32_bf16(afr[mt], bfr[nt], acc[mt][nt], 0, 0, 0);
    __syncthreads();
  }
  float bs[8];
#pragma unroll
  for (int nt = 0; nt < 8; nt++) bs[nt] = bsum[n0 + nt * 16 + l16];
#pragma unroll
  for (int mt = 0; mt < 2; mt++)
#pragma unroll
    for (int nt = 0; nt < 8; nt++)
#pragma unroll
      for (int i = 0; i < 4; i++) {
        const int gm = m0 + wave * 32 + mt * 16 + quad * 4 + i;
        Xpre[(size_t)gm * 512 + n0 + nt * 16 + l16] = acc[mt][nt][i] + bs[nt];
      }
}

// ---------- recurrence pass: LDS-only exchange, zero inter-wg communication ----------
// 4 wgs x 512 threads, wg owns batch rows 16*wg..+15. Wave wv owns hidden cols
// wv*64..+63 as 4 col-tiles of 16: tiles 0,1 resident in 128 VGPRs; tiles 2,3
// streamed from global each step (XCD-L2 resident: same 256KB every step) through
// a 64-reg double buffer, prefetched one round ahead. h kept as hi+lo bf16 in
// double-buffered LDS (ROWSP=522 -> 2-way free banking). LDS-only barrier keeps
// histhi stores + Xpre prefetch in flight across steps. Peak ~250 VGPRs, no spill.
__global__ __launch_bounds__(512, 2)
void rnn_lds(const u16* __restrict__ Whh, const float* __restrict__ Xpre,
             const int* __restrict__ lengths, u16* __restrict__ histhi,
             float* __restrict__ out_last, float* __restrict__ out_hidden) {
  __shared__ u16 Ab[2][2][16][ROWSP];   // [buf][hi/lo][row][col] = 66,816 B
  const int tid = threadIdx.x;
  const int wv = tid >> 6, lane = tid & 63;
  const int quad = lane >> 4, l16 = lane & 15;
  const int wg = blockIdx.x;
  const int colbase = wv * 64;

  // resident weights: col-tiles 0,1 -> wreg[nt][s] = W[colbase+nt*16+l16][s*32+quad*8 ..+7]
  bf16x8 wreg[2][16];
#pragma unroll
  for (int nt = 0; nt < 2; nt++) {
    const u16* wrow = Whh + (size_t)(colbase + nt * 16 + l16) * 512 + quad * 8;
#pragma unroll
    for (int s = 0; s < 16; s++)
      wreg[nt][s] = __builtin_bit_cast(bf16x8, *(const u16x8*)(wrow + s * 32));
  }
  // streamed tiles 2,3 per-lane base pointers
  const u16* wst2 = Whh + (size_t)(colbase + 32 + l16) * 512 + quad * 8;
  const u16* wst3 = Whh + (size_t)(colbase + 48 + l16) * 512 + quad * 8;

  int lens[4];
#pragma unroll
  for (int i = 0; i < 4; i++) lens[i] = lengths[wg * 16 + quad * 4 + i];

  // h(-1) = 0 in buffer 0
  for (int i = tid; i < 2 * 16 * ROWSP; i += 512) (&Ab[0][0][0][0])[i] = 0;
  __syncthreads();

  // Xpre for step 0
  float pre[4][4];
#pragma unroll
  for (int nt = 0; nt < 4; nt++)
#pragma unroll
    for (int i = 0; i < 4; i++)
      pre[nt][i] = Xpre[(size_t)(wg * 16 + quad * 4 + i) * 512 + colbase + nt * 16 + l16];

  // prefetch streamed round 0 (tile 2, s=0..7)
  bf16x8 wb[2][8];
#pragma unroll
  for (int j = 0; j < 8; j++)
    wb[0][j] = __builtin_bit_cast(bf16x8, *(const u16x8*)(wst2 + j * 32));

  for (int t = 0; t < TT; t++) {
    const int cur = t & 1, nxt = cur ^ 1;
    floatx4 ac[4];
#pragma unroll
    for (int nt = 0; nt < 4; nt++) ac[nt] = (floatx4){0.f, 0.f, 0.f, 0.f};

    const u16* ahi = &Ab[cur][0][l16][quad * 8];
    const u16* alo = &Ab[cur][1][l16][quad * 8];

    // ---- phase 1: resident tiles (64 MFMAs), hides round-0 stream RT
#pragma unroll
    for (int s = 0; s < 16; s++) {
      bf16x8 a0 = __builtin_bit_cast(bf16x8, *(const u16x8*)(ahi + s * 32));
      bf16x8 a1 = __builtin_bit_cast(bf16x8, *(const u16x8*)(alo + s * 32));
      ac[0] = __builtin_amdgcn_mfma_f32_16x16x32_bf16(a0, wreg[0][s], ac[0], 0, 0, 0);
      ac[1] = __builtin_amdgcn_mfma_f32_16x16x32_bf16(a0, wreg[1][s], ac[1], 0, 0, 0);
      ac[0] = __builtin_amdgcn_mfma_f32_16x16x32_bf16(a1, wreg[0][s], ac[0], 0, 0, 0);
      ac[1] = __builtin_amdgcn_mfma_f32_16x16x32_bf16(a1, wreg[1][s], ac[1], 0, 0, 0);
    }

    // fold pre into acc now, freeing the regs; then issue Xpre(t+1) prefetch into them
#pragma unroll
    for (int nt = 0; nt < 4; nt++)
#pragma unroll
      for (int i = 0; i < 4; i++) ac[nt][i] += pre[nt][i];
    {
      const int tp = (t + 1 < TT) ? t + 1 : TT - 1;
#pragma unroll
      for (int nt = 0; nt < 4; nt++)
#pragma unroll
        for (int i = 0; i < 4; i++)
          pre[nt][i] = Xpre[(size_t)(tp * 64 + wg * 16 + quad * 4 + i) * 512
                            + colbase + nt * 16 + l16];
    }

    // ---- phase 2: streamed tiles, 4 rounds of 8 frags, prefetch 1 round ahead
#pragma unroll
    for (int r = 0; r < 4; r++) {
      const int rb = r & 1;
      const u16* nsrc = (r == 0) ? (wst2 + 256) : (r == 1) ? wst3
                      : (r == 2) ? (wst3 + 256) : wst2;   // r==3 preloads next step's round 0
#pragma unroll
      for (int j = 0; j < 8; j++)
        wb[rb ^ 1][j] = __builtin_bit_cast(bf16x8, *(const u16x8*)(nsrc + j * 32));
      const int nt = 2 + (r >> 1);
      const int sb = (r & 1) * 8;
#pragma unroll
      for (int j = 0; j < 8; j++) {
        const int s = sb + j;
        bf16x8 a0 = __builtin_bit_cast(bf16x8, *(const u16x8*)(ahi + s * 32));
        bf16x8 a1 = __builtin_bit_cast(bf16x8, *(const u16x8*)(alo + s * 32));
        ac[nt] = __builtin_amdgcn_mfma_f32_16x16x32_bf16(a0, wb[rb][j], ac[nt], 0, 0, 0);
        ac[nt] = __builtin_amdgcn_mfma_f32_16x16x32_bf16(a1, wb[rb][j], ac[nt], 0, 0, 0);
      }
    }

    // ---- epilogue: tanh + mask (frozen h reconstructed from Ab[cur]) + write h(t)
#pragma unroll
    for (int nt = 0; nt < 4; nt++) {
      const int col = colbase + nt * 16 + l16;
#pragma unroll
      for (int i = 0; i < 4; i++) {
        const int row = quad * 4 + i;
        const float th = fast_tanh(ac[nt][i]);
        const float hold = bf2f(Ab[cur][0][row][col]) + bf2f(Ab[cur][1][row][col]);
        const float nv = (t < lens[i]) ? th : hold;
        const u16 hi = f2bf(nv);
        const u16 lo = f2bf(nv - bf2f(hi));
        Ab[nxt][0][row][col] = hi;
        Ab[nxt][1][row][col] = lo;
        if (histhi)
          histhi[(size_t)(t * 64 + wg * 16 + row) * 512 + col] = hi;
      }
    }
    LDS_BARRIER();
  }

  // final hidden state: h(T-1) lives in buffer (TT-1)&1 ^ 1 = 0
#pragma unroll
  for (int nt = 0; nt < 4; nt++) {
    const int col = colbase + nt * 16 + l16;
#pragma unroll
    for (int i = 0; i < 4; i++) {
      const int row = quad * 4 + i;
      const int b = wg * 16 + row;
      const float hv = bf2f(Ab[0][0][row][col]) + bf2f(Ab[0][1][row][col]);
      if (out_hidden) out_hidden[(size_t)b * 1024 + col] = hv;
      if (out_last)   out_last[(size_t)b * 512 + col] = hv;
    }
  }
}

// ---------- launch ----------
extern "C" void kernel_launch(void* const* d_in, const int* in_sizes, int n_in,
                              void* d_out, int out_size, void* d_ws, size_t ws_size,
                              hipStream_t stream) {
  const int*   x   = (const int*)d_in[0];
  const int*   len = (const int*)d_in[1];
  const float* emb = (const float*)d_in[2];
  const float* Wih = (const float*)d_in[3];
  const float* Whh = (const float*)d_in[4];
  const float* bih = (const float*)d_in[5];
  const float* bhh = (const float*)d_in[6];
  float* out = (float*)d_out;

  char* ws = (char*)d_ws;
  float* Xpre   = (float*)(ws);                  // 67,108,864 B (T*B*512 fp32), reused by both layers
  u16*   histhi = (u16*)(ws + 67108864);         // 33,554,432 B (T*B*512 bf16-hi of h0)
  u16*   wbf    = (u16*)(ws + 100663296);        //  2,097,152 B
  float* bsum   = (float*)(ws + 102760448);      //      4,096 B

  hipLaunchKernelGGL(prep_kernel, dim3(512), dim3(256), 0, stream,
                     Wih, Whh, bih, bhh, wbf, bsum);
  // layer 0 pre-activations: emb-gather GEMM
  hipLaunchKernelGGL(gemm_pre, dim3(1024), dim3(256), 0, stream,
                     wbf /*wih0*/, bsum, emb, x, (const u16*)nullptr, Xpre, 0);
  // layer 0 recurrence (writes h0-hi history for layer 1's pre-GEMM)
  hipLaunchKernelGGL(rnn_lds, dim3(4), dim3(512), 0, stream,
                     wbf + 262144 /*whh0*/, Xpre, len, histhi,
                     (float*)nullptr, out + 32768 /*hidden[:,0,:]*/);
  // layer 1 pre-activations: h0-hi GEMM
  hipLaunchKernelGGL(gemm_pre, dim3(1024), dim3(256), 0, stream,
                     wbf + 524288 /*wih1*/, bsum + 512,
                     (const float*)nullptr, (const int*)nullptr, histhi, Xpre, 1);
  // layer 1 recurrence
  hipLaunchKernelGGL(rnn_lds, dim3(4), dim3(512), 0, stream,
                     wbf + 786432 /*whh1*/, Xpre, len, (u16*)nullptr,
                     out /*h_last*/, out + 32768 + 512 /*hidden[:,1,:]*/);
}